// Round 3
// baseline (132.258 us; speedup 1.0000x reference)
//
#include <hip/hip_runtime.h>
#include <hip/hip_bf16.h>

using u16 = unsigned short;
using u32 = unsigned int;

typedef __attribute__((ext_vector_type(8)))  short s16x8;
typedef __attribute__((ext_vector_type(4)))  float f32x4;
typedef __attribute__((ext_vector_type(16))) float f32x16;
typedef __attribute__((ext_vector_type(4)))  u32   u32x4;

#define NQ 74                      // K chunks of 32 (2368 padded features)
#define WG_U16   (NQ * 2 * 4096)   // 74*2*4096 u16 = 606208 weights
#define RUNPK_OFF (WG_U16 * 2)     // byte offset of runpk[] in d_ws

__device__ __forceinline__ u16 f2bf_rne(float f) {
    u32 u = __builtin_bit_cast(u32, f);
    u32 r = u + 0x7fffu + ((u >> 16) & 1u);
    return (u16)(r >> 16);
}
__device__ __forceinline__ float bf2f(u16 u) {
    u32 v = ((u32)u) << 16;
    return __builtin_bit_cast(float, v);
}

// run r -> (i, j0). r<8: linear terms (i=64 = "ones"); else quad row i,
// runs start at j0=(i>>3)*8 (leading j<i entries carry zero weights).
__device__ __forceinline__ void run_decode(int r, int& i, int& j0) {
    if (r < 8) { i = 64; j0 = r << 3; return; }
    int rr = r - 8;
    int ii = 0;
    while (true) { int cnt = 8 - (ii >> 3); if (rr < cnt) break; rr -= cnt; ++ii; }
    i = ii;
    j0 = ((ii >> 3) << 3) + (rr << 3);
}

// fc_w [256][2144] f32 -> wg bf16, layout [q][nh][ni][ks][l][e] (u16 linear).
// n = nh*128 + ni*32 + (l&31); run = q*4 + ks*2 + (l>>5); k-elem e=0..7.
// One weight per thread: coalesced load AND store.
__global__ __launch_bounds__(1024)
void pack_w(const float* __restrict__ fcw, u16* __restrict__ wg,
            u32* __restrict__ runpk) {
    if (blockIdx.x == 0 && threadIdx.x < NQ * 2) {
        int q = threadIdx.x >> 1, ks = threadIdx.x & 1;
        int i0, j00, i1, j01;
        run_decode(q * 4 + ks * 2 + 0, i0, j00);
        run_decode(q * 4 + ks * 2 + 1, i1, j01);
        runpk[threadIdx.x] =
            ((u32)i0 << 24) | ((u32)j00 << 16) | ((u32)i1 << 8) | (u32)j01;
    }
    const u32 g  = blockIdx.x * 1024 + threadIdx.x;   // 592*1024 == WG_U16
    const int e  = g & 7;
    const int l  = (g >> 3) & 63;
    const int ks = (g >> 9) & 1;
    const int ni = (g >> 10) & 3;
    const int nh = (g >> 12) & 1;
    const int q  = g >> 13;
    const int kh = l >> 5;
    int i, j0; run_decode(q * 4 + ks * 2 + kh, i, j0);
    const int n = nh * 128 + ni * 32 + (l & 31);
    const int j = j0 + e;
    float w;
    if (i == 64)    w = fcw[n * 2144 + j];
    else if (j < i) w = 0.f;
    else            w = fcw[n * 2144 + 64 + i * 64 - ((i * (i - 1)) >> 1) + (j - i)];
    wg[g] = f2bf_rne(w);
}

// y[e] = x[m][i] * x[m][j0+e], truncating f32->bf16 pack
__device__ __forceinline__ s16x8 packmul(float fi, s16x8 vj) {
    u32 pk[4];
    #pragma unroll
    for (int d = 0; d < 4; ++d) {
        float p0 = fi * bf2f((u16)vj[2 * d]);
        float p1 = fi * bf2f((u16)vj[2 * d + 1]);
        pk[d] = __builtin_amdgcn_perm(__builtin_bit_cast(u32, p1),
                                      __builtin_bit_cast(u32, p0), 0x07060302u);
    }
    u32x4 pv = { pk[0], pk[1], pk[2], pk[3] };
    return __builtin_bit_cast(s16x8, pv);
}

__global__ __launch_bounds__(512, 2)
void quad_gemm(const float* __restrict__ x, const s16x8* __restrict__ wg16,
               const u32* __restrict__ runpk, float* __restrict__ out) {
    __shared__ __align__(16) u16   x_lds[256 * 64];   // [m][c^sw], 16B-XOR swizzle
    __shared__ __align__(16) u16   x_t[64 * 256];     // [c][m] transposed copy
    __shared__ __align__(16) s16x8 wbuf[3][512];      // triple-buffered W chunk
    __shared__ u32 runl[NQ * 2];

    const int t   = threadIdx.x;
    const int l   = t & 63;
    const int wv  = t >> 6;
    const int rr  = wv >> 1;          // M-row 0..3 (64 px each)
    const int cc  = wv & 1;           // N-col 0..1 (64 out each)
    const int kh  = l >> 5;
    const int lm  = l & 31;
    const int sw8 = (l & 7) << 3;

    const int mtile = blockIdx.x >> 1;
    const int nb    = blockIdx.x & 1;    // N half (128 outputs)
    const int pix0  = mtile * 256;
    const int b     = pix0 >> 12;
    const int hw0   = pix0 & 4095;

    if (t < NQ * 2) runl[t] = runpk[t];

    // ---- stage x tile (256 px x 64 ch): f32 -> bf16, both layouts
    {
        const int mg = (t & 63) << 2;         // 4 consecutive pixels
        const int cg = (t >> 6) << 3;         // 8 consecutive channels
        const float* xp = x + ((size_t)b << 18) + hw0 + mg;
        f32x4 vv[8];
        #pragma unroll
        for (int e = 0; e < 8; ++e)
            vv[e] = *(const f32x4*)(xp + ((size_t)(cg + e) << 12));
        u16 tb[8][4];
        #pragma unroll
        for (int e = 0; e < 8; ++e)
            #pragma unroll
            for (int r = 0; r < 4; ++r) tb[e][r] = f2bf_rne(vv[e][r]);
        #pragma unroll
        for (int r = 0; r < 4; ++r) {
            int m = mg + r;
            s16x8 pv = { (short)tb[0][r], (short)tb[1][r], (short)tb[2][r],
                         (short)tb[3][r], (short)tb[4][r], (short)tb[5][r],
                         (short)tb[6][r], (short)tb[7][r] };
            *(s16x8*)(x_lds + (m << 6) + (cg ^ ((m & 7) << 3))) = pv;
        }
        #pragma unroll
        for (int e = 0; e < 8; ++e) {
            typedef __attribute__((ext_vector_type(4))) short s16x4;
            s16x4 pv = { (short)tb[e][0], (short)tb[e][1],
                         (short)tb[e][2], (short)tb[e][3] };
            *(s16x4*)(x_t + ((cg + e) << 8) + mg) = pv;
        }
    }

    char* wb0 = (char*)&wbuf[0][0];
    char* wb1 = (char*)&wbuf[1][0];
    char* wb2 = (char*)&wbuf[2][0];
    const s16x8* wsrc = wg16 + nb * 512 + t;

    #define STAGEQ(Q, DST) __builtin_amdgcn_global_load_lds(                 \
        (const __attribute__((address_space(1))) void*)(wsrc + (size_t)(Q) * 1024), \
        (__attribute__((address_space(3))) void*)((DST) + wv * 1024), 16, 0, 0)

    STAGEQ(0, wb0);
    STAGEQ(1, wb1);

    const int xrow0 = (rr * 64 + lm) << 6;
    const int xrow1 = (rr * 64 + 32 + lm) << 6;
    const int mt0   = rr * 64 + lm;          // x_t pixel index for mi=0

    f32x16 acc00, acc01, acc10, acc11;
    #pragma unroll
    for (int r = 0; r < 16; ++r) {
        acc00[r] = 0.f; acc01[r] = 0.f; acc10[r] = 0.f; acc11[r] = 0.f;
    }

    // Y generation for chunk Q (per-lane, from resident x LDS)
    #define GENQ(Q, Y00_, Y01_, Y10_, Y11_) do {                             \
        u32 rp0_ = runl[(Q) * 2], rp1_ = runl[(Q) * 2 + 1];                  \
        u32 ij0_ = kh ? (rp0_ & 0xffffu) : (rp0_ >> 16);                     \
        u32 ij1_ = kh ? (rp1_ & 0xffffu) : (rp1_ >> 16);                     \
        int ia_ = (int)(ij0_ >> 8), ja_ = (int)(ij0_ & 255u) ^ sw8;          \
        int ib_ = (int)(ij1_ >> 8), jb_ = (int)(ij1_ & 255u) ^ sw8;         \
        float fa0_ = (ia_ >= 64) ? 1.0f : bf2f(x_t[((ia_ & 63) << 8) + mt0]);      \
        float fa1_ = (ia_ >= 64) ? 1.0f : bf2f(x_t[((ia_ & 63) << 8) + mt0 + 32]); \
        float fb0_ = (ib_ >= 64) ? 1.0f : bf2f(x_t[((ib_ & 63) << 8) + mt0]);      \
        float fb1_ = (ib_ >= 64) ? 1.0f : bf2f(x_t[((ib_ & 63) << 8) + mt0 + 32]); \
        Y00_ = packmul(fa0_, *(const s16x8*)(x_lds + xrow0 + ja_));          \
        Y10_ = packmul(fa1_, *(const s16x8*)(x_lds + xrow1 + ja_));          \
        Y01_ = packmul(fb0_, *(const s16x8*)(x_lds + xrow0 + jb_));          \
        Y11_ = packmul(fb1_, *(const s16x8*)(x_lds + xrow1 + jb_));          \
    } while (0)

    asm volatile("s_waitcnt lgkmcnt(0)" ::: "memory");  // x LDS writes drained
    __builtin_amdgcn_s_barrier();
    asm volatile("" ::: "memory");

    s16x8 Y00, Y01, Y10, Y11;      // Y[mi][ks] for current chunk
    GENQ(0, Y00, Y01, Y10, Y11);

    for (int q = 0; q < NQ; ++q) {
        if (q == NQ - 1) { asm volatile("s_waitcnt vmcnt(0)" ::: "memory"); }
        else             { asm volatile("s_waitcnt vmcnt(1)" ::: "memory"); }
        __builtin_amdgcn_s_barrier();
        asm volatile("" ::: "memory");

        const s16x8* wbp = (const s16x8*)wb0;
        s16x8 W00 = wbp[(cc * 4 + 0) * 64 + l];   // [ni=0][ks=0]
        s16x8 W01 = wbp[(cc * 4 + 1) * 64 + l];   // [ni=0][ks=1]
        s16x8 W10 = wbp[(cc * 4 + 2) * 64 + l];   // [ni=1][ks=0]
        s16x8 W11 = wbp[(cc * 4 + 3) * 64 + l];   // [ni=1][ks=1]

        if (q < NQ - 2) STAGEQ(q + 2, wb2);

        acc00 = __builtin_amdgcn_mfma_f32_32x32x16_bf16(W00, Y00, acc00, 0, 0, 0);
        acc00 = __builtin_amdgcn_mfma_f32_32x32x16_bf16(W01, Y01, acc00, 0, 0, 0);
        acc01 = __builtin_amdgcn_mfma_f32_32x32x16_bf16(W10, Y00, acc01, 0, 0, 0);
        acc01 = __builtin_amdgcn_mfma_f32_32x32x16_bf16(W11, Y01, acc01, 0, 0, 0);
        acc10 = __builtin_amdgcn_mfma_f32_32x32x16_bf16(W00, Y10, acc10, 0, 0, 0);
        acc10 = __builtin_amdgcn_mfma_f32_32x32x16_bf16(W01, Y11, acc10, 0, 0, 0);
        acc11 = __builtin_amdgcn_mfma_f32_32x32x16_bf16(W10, Y10, acc11, 0, 0, 0);
        acc11 = __builtin_amdgcn_mfma_f32_32x32x16_bf16(W11, Y11, acc11, 0, 0, 0);

        if (q < NQ - 1) GENQ(q + 1, Y00, Y01, Y10, Y11);  // overlap with MFMA

        char* tmpp = wb0; wb0 = wb1; wb1 = wb2; wb2 = tmpp;
    }

    // D (A=W rows=out, B=Y cols=px): col = lane&31 -> pixel,
    // row = (r&3) + 8*(r>>2) + 4*kh -> output channel
    float* ob = out + ((size_t)b << 20) + (size_t)hw0;
    const int ob0 = nb * 128 + cc * 64 + kh * 4;
    #pragma unroll
    for (int r = 0; r < 16; ++r) {
        const int o = ob0 + (r & 3) + 8 * (r >> 2);
        ob[(size_t)o * 4096 + mt0]             = acc00[r];
        ob[(size_t)(o + 32) * 4096 + mt0]      = acc01[r];
        ob[(size_t)o * 4096 + mt0 + 32]        = acc10[r];
        ob[(size_t)(o + 32) * 4096 + mt0 + 32] = acc11[r];
    }
}

extern "C" void kernel_launch(void* const* d_in, const int* in_sizes, int n_in,
                              void* d_out, int out_size, void* d_ws, size_t ws_size,
                              hipStream_t stream) {
    const float* x   = (const float*)d_in[0];
    const float* fcw = (const float*)d_in[1];
    float* out = (float*)d_out;
    u16* wg    = (u16*)d_ws;                              // 1.21 MB
    u32* runpk = (u32*)((char*)d_ws + RUNPK_OFF);         // 592 B

    hipLaunchKernelGGL(pack_w, dim3(WG_U16 / 1024), dim3(1024), 0, stream,
                       fcw, wg, runpk);
    hipLaunchKernelGGL(quad_gemm, dim3(256), dim3(512), 0, stream,
                       x, (const s16x8*)wg, runpk, out);
}

// Round 4
// 129.002 us; speedup vs baseline: 1.0252x; 1.0252x over previous
//
#include <hip/hip_runtime.h>
#include <hip/hip_bf16.h>

using u16 = unsigned short;
using u32 = unsigned int;

typedef __attribute__((ext_vector_type(8)))  short s16x8;
typedef __attribute__((ext_vector_type(2)))  float f32x2;
typedef __attribute__((ext_vector_type(16))) float f32x16;
typedef __attribute__((ext_vector_type(4)))  u32   u32x4;

#define NQ 74                      // K chunks of 32 (2368 padded features)
#define WG_U16   (NQ * 2 * 4096)   // 74*2*4096 u16 = 606208 weights
#define RUNPK_OFF (WG_U16 * 2)     // byte offset of runpk[] in d_ws

__device__ __forceinline__ u16 f2bf_rne(float f) {
    u32 u = __builtin_bit_cast(u32, f);
    u32 r = u + 0x7fffu + ((u >> 16) & 1u);
    return (u16)(r >> 16);
}
__device__ __forceinline__ float bf2f(u16 u) {
    u32 v = ((u32)u) << 16;
    return __builtin_bit_cast(float, v);
}

// run r -> (i, j0). r<8: linear terms (i=64 = "ones"); else quad row i,
// runs start at j0=(i>>3)*8 (leading j<i entries carry zero weights).
__device__ __forceinline__ void run_decode(int r, int& i, int& j0) {
    if (r < 8) { i = 64; j0 = r << 3; return; }
    int rr = r - 8;
    int ii = 0;
    while (true) { int cnt = 8 - (ii >> 3); if (rr < cnt) break; rr -= cnt; ++ii; }
    i = ii;
    j0 = ((ii >> 3) << 3) + (rr << 3);
}

// fc_w [256][2144] f32 -> wg bf16, layout [q][nh][ni][ks][l][e] (u16 linear).
// n = nh*128 + ni*32 + (l&31); run = q*4 + ks*2 + (l>>5); k-elem e=0..7.
// q = g>>13 is block-uniform: decode the block's 4 runs once into LDS.
__global__ __launch_bounds__(1024)
void pack_w(const float* __restrict__ fcw, u16* __restrict__ wg,
            u32* __restrict__ runpk) {
    __shared__ u16 runs4[4];
    const int q = blockIdx.x >> 3;             // 8 blocks per q
    const int t = threadIdx.x;
    if (t < 4) {
        int i, j0; run_decode(q * 4 + t, i, j0);
        runs4[t] = (u16)((i << 8) | j0);
        if ((blockIdx.x & 7) == 0 && t < 2) {
            int ia, ja, ib, jb;
            run_decode(q * 4 + t * 2 + 0, ia, ja);
            run_decode(q * 4 + t * 2 + 1, ib, jb);
            runpk[q * 2 + t] =
                ((u32)ia << 24) | ((u32)ja << 16) | ((u32)ib << 8) | (u32)jb;
        }
    }
    __syncthreads();
    const u32 g  = blockIdx.x * 1024 + t;
    const int e  = g & 7;
    const int l  = (g >> 3) & 63;
    const int ks = (g >> 9) & 1;
    const int ni = (g >> 10) & 3;
    const int nh = (g >> 12) & 1;
    const int kh = l >> 5;
    const u16 ij = runs4[ks * 2 + kh];
    const int i = ij >> 8, j0 = ij & 255;
    const int n = nh * 128 + ni * 32 + (l & 31);
    const int j = j0 + e;
    float w;
    if (i == 64)    w = fcw[n * 2144 + j];
    else if (j < i) w = 0.f;
    else            w = fcw[n * 2144 + 64 + i * 64 - ((i * (i - 1)) >> 1) + (j - i)];
    wg[g] = f2bf_rne(w);
}

// y[e] = x[m][i] * x[m][j0+e], truncating f32->bf16 pack
__device__ __forceinline__ s16x8 packmul(float fi, s16x8 vj) {
    u32 pk[4];
    #pragma unroll
    for (int d = 0; d < 4; ++d) {
        float p0 = fi * bf2f((u16)vj[2 * d]);
        float p1 = fi * bf2f((u16)vj[2 * d + 1]);
        pk[d] = __builtin_amdgcn_perm(__builtin_bit_cast(u32, p1),
                                      __builtin_bit_cast(u32, p0), 0x07060302u);
    }
    u32x4 pv = { pk[0], pk[1], pk[2], pk[3] };
    return __builtin_bit_cast(s16x8, pv);
}

__global__ __launch_bounds__(512, 4)
void quad_gemm(const float* __restrict__ x, const u16* __restrict__ wg,
               const u32* __restrict__ runpk, float* __restrict__ out) {
    __shared__ __align__(16) u16 x_lds[128 * 64];   // [m][c^sw], 16B-XOR swizzle
    __shared__ __align__(16) u16 wbuf[3][4096];     // rolling W chunk (8 KB each)
    __shared__ u32 runl[NQ * 2];

    const int t   = threadIdx.x;
    const int l   = t & 63;
    const int wv  = t >> 6;           // 8 waves
    const int mrow = wv >> 1;         // 0..3 -> 32-px row
    const int nc   = wv & 1;          // 0..1 -> 64-out col
    const int kh  = l >> 5;
    const int lm  = l & 31;
    const int sw8 = (lm & 7) << 3;

    const int mtile = blockIdx.x >> 1;
    const int nb    = blockIdx.x & 1;    // N half (128 outputs)
    const int pix0  = mtile * 128;
    const int b     = pix0 >> 12;
    const int hw0   = pix0 & 4095;

    if (t < NQ * 2) runl[t] = runpk[t];

    // ---- stage x tile (128 px x 64 ch): f32 -> bf16, swizzled LDS
    {
        const int mg = (t & 63) << 1;         // 2 consecutive pixels
        const int cg = (t >> 6) << 3;         // 8 consecutive channels
        const float* xp = x + ((size_t)b << 18) + hw0 + mg;
        f32x2 vv[8];
        #pragma unroll
        for (int e = 0; e < 8; ++e)
            vv[e] = *(const f32x2*)(xp + ((size_t)(cg + e) << 12));
        #pragma unroll
        for (int r = 0; r < 2; ++r) {
            int m = mg + r;
            s16x8 pv = { (short)f2bf_rne(vv[0][r]), (short)f2bf_rne(vv[1][r]),
                         (short)f2bf_rne(vv[2][r]), (short)f2bf_rne(vv[3][r]),
                         (short)f2bf_rne(vv[4][r]), (short)f2bf_rne(vv[5][r]),
                         (short)f2bf_rne(vv[6][r]), (short)f2bf_rne(vv[7][r]) };
            *(s16x8*)(x_lds + (m << 6) + (cg ^ ((m & 7) << 3))) = pv;
        }
    }

    // prologue W staging: chunk 0 -> wbuf0, chunk 1 -> wbuf1 (own-wave slots)
    const u16* wsrc = wg + (size_t)nb * 4096 + t * 8;   // +q*8192
    char* wb0 = (char*)&wbuf[0][0];
    char* wb1 = (char*)&wbuf[1][0];
    char* wb2 = (char*)&wbuf[2][0];
    #define STAGEQ(Q, DST) __builtin_amdgcn_global_load_lds(                  \
        (const __attribute__((address_space(1))) void*)(wsrc + (size_t)(Q) * 8192), \
        (__attribute__((address_space(3))) void*)((DST) + t * 16), 16, 0, 0)
    STAGEQ(0, wb0);
    STAGEQ(1, wb1);

    const int xrow = (mrow * 32 + lm) << 6;

    f32x16 acc0, acc1;
    #pragma unroll
    for (int r = 0; r < 16; ++r) { acc0[r] = 0.f; acc1[r] = 0.f; }

    // Y generation for chunk Q (per-lane, from resident x_lds)
    #define GENQ(Q, Y0_, Y1_) do {                                           \
        u32 rp0_ = runl[(Q) * 2], rp1_ = runl[(Q) * 2 + 1];                  \
        u32 ij0_ = kh ? (rp0_ & 0xffffu) : (rp0_ >> 16);                     \
        u32 ij1_ = kh ? (rp1_ & 0xffffu) : (rp1_ >> 16);                     \
        int ia_ = (int)(ij0_ >> 8), ja_ = (int)(ij0_ & 255u) ^ sw8;          \
        int ib_ = (int)(ij1_ >> 8), jb_ = (int)(ij1_ & 255u) ^ sw8;          \
        float fa_ = (ia_ >= 64) ? 1.0f : bf2f(x_lds[xrow + ((ia_ & 63) ^ sw8)]); \
        float fb_ = (ib_ >= 64) ? 1.0f : bf2f(x_lds[xrow + ((ib_ & 63) ^ sw8)]); \
        Y0_ = packmul(fa_, *(const s16x8*)(x_lds + xrow + ja_));             \
        Y1_ = packmul(fb_, *(const s16x8*)(x_lds + xrow + jb_));             \
    } while (0)

    // One step of the K loop. Invariant on entry: wb0 holds chunk Q (in
    // flight), wb1 holds Q+1 (in flight), wb2 is free.
    #define STEP(Q, YC0, YC1, YN0, YN1, LAST) do {                           \
        if (LAST) { asm volatile("s_waitcnt vmcnt(0)" ::: "memory"); }       \
        else      { asm volatile("s_waitcnt vmcnt(1)" ::: "memory"); }       \
        __builtin_amdgcn_s_barrier();                                        \
        asm volatile("" ::: "memory");                                       \
        if ((Q) + 2 < NQ) STAGEQ((Q) + 2, wb2);                              \
        const s16x8* wbp_ = (const s16x8*)wb0;                               \
        s16x8 W00_ = wbp_[(nc * 4 + 0) * 64 + l];                            \
        s16x8 W01_ = wbp_[(nc * 4 + 1) * 64 + l];                            \
        s16x8 W10_ = wbp_[(nc * 4 + 2) * 64 + l];                            \
        s16x8 W11_ = wbp_[(nc * 4 + 3) * 64 + l];                            \
        if (!(LAST)) GENQ((Q) + 1, YN0, YN1);                                \
        acc0 = __builtin_amdgcn_mfma_f32_32x32x16_bf16(W00_, YC0, acc0, 0, 0, 0); \
        acc0 = __builtin_amdgcn_mfma_f32_32x32x16_bf16(W01_, YC1, acc0, 0, 0, 0); \
        acc1 = __builtin_amdgcn_mfma_f32_32x32x16_bf16(W10_, YC0, acc1, 0, 0, 0); \
        acc1 = __builtin_amdgcn_mfma_f32_32x32x16_bf16(W11_, YC1, acc1, 0, 0, 0); \
        char* tp_ = wb0; wb0 = wb1; wb1 = wb2; wb2 = tp_;                    \
    } while (0)

    __syncthreads();      // x_lds + runl ready

    s16x8 Ya0, Ya1, Yb0, Yb1;
    GENQ(0, Ya0, Ya1);
    for (int q = 0; q < NQ - 2; q += 2) {
        STEP(q,     Ya0, Ya1, Yb0, Yb1, false);
        STEP(q + 1, Yb0, Yb1, Ya0, Ya1, false);
    }
    STEP(NQ - 2, Ya0, Ya1, Yb0, Yb1, false);
    STEP(NQ - 1, Yb0, Yb1, Ya0, Ya1, true);

    // D (A=W rows=out, B=Y cols=px): col = lane&31 -> pixel,
    // row = (r&3) + 8*(r>>2) + 4*kh -> output channel (within 32-row tile)
    float* ob = out + ((size_t)b << 20) + (size_t)hw0;
    const int px = mrow * 32 + lm;
    #pragma unroll
    for (int r = 0; r < 16; ++r) {
        const int o = nb * 128 + nc * 64 + kh * 4 + (r & 3) + 8 * (r >> 2);
        ob[(size_t)o * 4096 + px]        = acc0[r];
        ob[(size_t)(o + 32) * 4096 + px] = acc1[r];
    }
}

extern "C" void kernel_launch(void* const* d_in, const int* in_sizes, int n_in,
                              void* d_out, int out_size, void* d_ws, size_t ws_size,
                              hipStream_t stream) {
    const float* x   = (const float*)d_in[0];
    const float* fcw = (const float*)d_in[1];
    float* out = (float*)d_out;
    u16* wg    = (u16*)d_ws;                              // 1.21 MB
    u32* runpk = (u32*)((char*)d_ws + RUNPK_OFF);         // 592 B

    hipLaunchKernelGGL(pack_w, dim3(WG_U16 / 1024), dim3(1024), 0, stream,
                       fcw, wg, runpk);
    hipLaunchKernelGGL(quad_gemm, dim3(512), dim3(512), 0, stream,
                       x, wg, runpk, out);
}

// Round 7
// 114.666 us; speedup vs baseline: 1.1534x; 1.1250x over previous
//
#include <hip/hip_runtime.h>

using u16 = unsigned short;
using u32 = unsigned int;

typedef __attribute__((ext_vector_type(8)))  short s16x8;
typedef __attribute__((ext_vector_type(4)))  float f32x4;
typedef __attribute__((ext_vector_type(16))) float f32x16;
typedef __attribute__((ext_vector_type(4)))  u32   u32x4;

#define NQ  74       // K chunks of 32 (2368 padded features)
#define NQQ 72       // quad chunks (column-major jr blocks); 72,73 = linear
#define WG_U16   (NQ * 8192)         // 606208 bf16 weights
#define RUNPK_OFF (WG_U16 * 2)       // byte offset of runpk[] in d_ws

__device__ __forceinline__ u16 f2bf_rne(float f) {
    u32 u = __builtin_bit_cast(u32, f);
    u32 r = u + 0x7fffu + ((u >> 16) & 1u);
    return (u16)(r >> 16);
}
__device__ __forceinline__ float bf2f(u16 u) {
    u32 v = ((u32)u) << 16;
    return __builtin_bit_cast(float, v);
}

// Column-major run schedule. Global run r (0..295):
//  r < 288: quad. chunk c=r>>2 lies in jr-block [jr(jr+1), (jr+1)(jr+2));
//           i = 4*(c - jr(jr+1)) + (r&3), j0 = 8*jr.  (j<i elems zero-padded)
//  r >= 288: linear (i = "ones"), j0 = 8*(r-288).
__device__ __forceinline__ void cm_decode(int r, int& i, int& j0) {
    if (r >= 288) { i = 64; j0 = (r - 288) * 8; return; }
    int c = r >> 2;
    int jr = 0;
    while (jr < 7 && (jr + 1) * (jr + 2) <= c) ++jr;
    i  = 4 * (c - jr * (jr + 1)) + (r & 3);
    j0 = 8 * jr;
}

// fc_w [256][2144] f32 -> wg bf16, flat idx
//   g = q*8192 + nb*4096 + nc*2048 + s*1024 + ni*512 + l*8 + e
// out-row n = nb*128 + nc*64 + ni*32 + (l&31); run = q*4 + 2s + (l>>5); elem e.
__global__ __launch_bounds__(1024)
void pack_w(const float* __restrict__ fcw, u16* __restrict__ wg,
            u32* __restrict__ runpk) {
    const u32 g = blockIdx.x * 1024 + threadIdx.x;
    if (blockIdx.x == 0 && threadIdx.x < NQQ) {
        int q = threadIdx.x, jr = 0;
        while (jr < 7 && (jr + 1) * (jr + 2) <= q) ++jr;
        runpk[q] = ((u32)(8 * jr) << 8) | (u32)(4 * (q - jr * (jr + 1)));
    }
    const int e  = g & 7;
    const int l  = (g >> 3) & 63;
    const int kh = l >> 5;
    const int ni = (g >> 9) & 1, s = (g >> 10) & 1;
    const int nc = (g >> 11) & 1, nb = (g >> 12) & 1;
    const int q  = g >> 13;
    int i, j0; cm_decode(q * 4 + 2 * s + kh, i, j0);
    const int n = nb * 128 + nc * 64 + ni * 32 + (l & 31);
    const int j = j0 + e;
    float w;
    if (i == 64)    w = fcw[n * 2144 + j];                                     // linear
    else if (j < i) w = 0.f;                                                   // pad
    else            w = fcw[n * 2144 + 64 + i * 64 - ((i * (i - 1)) >> 1) + (j - i)];
    wg[g] = f2bf_rne(w);
}

// y[e] = fi * x[j0+e], f32 mul + truncating bf16 pack (R1-R4 proven)
__device__ __forceinline__ s16x8 packmul(float fi, s16x8 vj) {
    u32 pk[4];
    #pragma unroll
    for (int d = 0; d < 4; ++d) {
        float p0 = fi * bf2f((u16)vj[2 * d]);
        float p1 = fi * bf2f((u16)vj[2 * d + 1]);
        pk[d] = __builtin_amdgcn_perm(__builtin_bit_cast(u32, p1),
                                      __builtin_bit_cast(u32, p0), 0x07060302u);
    }
    u32x4 pv = { pk[0], pk[1], pk[2], pk[3] };
    return __builtin_bit_cast(s16x8, pv);
}

__global__ __launch_bounds__(256, 2)
void quad_gemm(const float* __restrict__ x, const u16* __restrict__ wg,
               const u32* __restrict__ runpk, float* __restrict__ out) {
    __shared__ __align__(16) u16 xl[128 * 64];   // bf16 [px][c ^ ((px&7)<<3)]

    const int t  = threadIdx.x;
    const int l  = t & 63;
    const int wv = t >> 6;            // 4 waves: 2 mrow x 2 nc
    const int mrow = wv >> 1, nc = wv & 1;
    const int lm = l & 31, kh = l >> 5;
    const int sw = (lm & 7) << 3;

    const int mtile = (int)blockIdx.x >> 1;
    const int nb    = blockIdx.x & 1;         // N half (128 outputs)
    const int pix0  = mtile * 128;
    const int b     = pix0 >> 12;
    const int hw0   = pix0 & 4095;

    // ---- stage x tile (128 px x 64 ch), f32 -> bf16, XOR-swizzled
    {
        const int mg = (t & 31) * 4;          // 4 consecutive pixels
        const int cg = (t >> 5) * 8;          // 8 consecutive channels
        const float* xp = x + ((size_t)b << 18) + (size_t)cg * 4096 + hw0 + mg;
        f32x4 vv[8];
        #pragma unroll
        for (int e = 0; e < 8; ++e)
            vv[e] = *(const f32x4*)(xp + (size_t)e * 4096);
        #pragma unroll
        for (int r = 0; r < 4; ++r) {
            u32 w4[4];
            #pragma unroll
            for (int d = 0; d < 4; ++d)
                w4[d] = (u32)f2bf_rne(vv[2 * d][r]) |
                        ((u32)f2bf_rne(vv[2 * d + 1][r]) << 16);
            int m = mg + r;
            u32x4 pv = { w4[0], w4[1], w4[2], w4[3] };
            *(u32x4*)(xl + m * 64 + (cg ^ ((m & 7) << 3))) = pv;
        }
    }

    const int pxb = mrow * 64 + lm;
    const u16* wp = wg + (size_t)(nb * 2 + nc) * 2048 + (size_t)l * 8;

    f32x16 acc[2][2];
    #pragma unroll
    for (int mi = 0; mi < 2; ++mi)
        #pragma unroll
        for (int ni = 0; ni < 2; ++ni)
            #pragma unroll
            for (int r = 0; r < 16; ++r) acc[mi][ni][r] = 0.f;

    // W chunk -> 4 frags in regs (W[s*2+ni]), coalesced dwordx4 from L2
    #define LOADW(Q, W) do {                                                 \
        const u32x4* p_ = (const u32x4*)(wp + (size_t)(Q) * 8192);           \
        W[0] = p_[0]; W[1] = p_[64]; W[2] = p_[128]; W[3] = p_[192];         \
    } while (0)

    // Y frags for chunk Q (Y[mi*2+s]): per-lane from resident xl, no barriers
    #define GENQ(Q, Y) do {                                                  \
        if ((Q) < NQQ) {                                                     \
            u32 meta_ = runpk[(Q)];                                          \
            int j0_ = (int)((meta_ >> 8) & 255u), ib_ = (int)(meta_ & 255u); \
            _Pragma("unroll")                                                \
            for (int mi_ = 0; mi_ < 2; ++mi_) {                              \
                int base_ = (pxb + mi_ * 32) * 64;                           \
                s16x8 vj_ = *(const s16x8*)(xl + base_ + (j0_ ^ sw));        \
                float f0_ = bf2f(xl[base_ + ((ib_ + kh) ^ sw)]);             \
                float f1_ = bf2f(xl[base_ + ((ib_ + 2 + kh) ^ sw)]);         \
                Y[mi_ * 2 + 0] = packmul(f0_, vj_);                          \
                Y[mi_ * 2 + 1] = packmul(f1_, vj_);                          \
            }                                                                \
        } else {                                                             \
            int cb_ = ((Q) - NQQ) * 32;                                      \
            _Pragma("unroll")                                                \
            for (int mi_ = 0; mi_ < 2; ++mi_) {                              \
                int base_ = (pxb + mi_ * 32) * 64;                           \
                _Pragma("unroll")                                            \
                for (int s_ = 0; s_ < 2; ++s_) {                             \
                    int j0_ = cb_ + 8 * (2 * s_ + kh);                       \
                    Y[mi_ * 2 + s_] =                                        \
                        *(const s16x8*)(xl + base_ + (j0_ ^ sw));            \
                }                                                            \
            }                                                                \
        }                                                                    \
    } while (0)

    #define MFMAQ(W, Y) do {                                                 \
        _Pragma("unroll")                                                    \
        for (int s_ = 0; s_ < 2; ++s_)                                       \
            _Pragma("unroll")                                                \
            for (int mi_ = 0; mi_ < 2; ++mi_)                                \
                _Pragma("unroll")                                            \
                for (int ni_ = 0; ni_ < 2; ++ni_)                            \
                    acc[mi_][ni_] = __builtin_amdgcn_mfma_f32_32x32x16_bf16( \
                        __builtin_bit_cast(s16x8, W[s_ * 2 + ni_]),          \
                        Y[mi_ * 2 + s_],                                     \
                        acc[mi_][ni_], 0, 0, 0);                             \
    } while (0)

    u32x4 Wa[4], Wb[4];
    s16x8 Ya[4], Yb[4];

    LOADW(0, Wa);
    __syncthreads();          // xl ready; the ONLY barrier
    GENQ(0, Ya);

    #pragma unroll 1
    for (int q = 0; q + 2 < NQ; q += 2) {
        LOADW(q + 1, Wb);
        GENQ(q + 1, Yb);
        MFMAQ(Wa, Ya);
        LOADW(q + 2, Wa);
        GENQ(q + 2, Ya);
        MFMAQ(Wb, Yb);
    }
    // Wa/Ya hold chunk 72
    LOADW(NQ - 1, Wb);
    GENQ(NQ - 1, Yb);
    MFMAQ(Wa, Ya);
    MFMAQ(Wb, Yb);

    // D: col = lane&31 -> pixel; row = (r&3) + 8*(r>>2) + 4*kh -> out channel
    float* ob = out + ((size_t)b << 20) + (size_t)hw0;
    #pragma unroll
    for (int mi = 0; mi < 2; ++mi) {
        const int px = pxb + mi * 32;
        #pragma unroll
        for (int ni = 0; ni < 2; ++ni) {
            #pragma unroll
            for (int r = 0; r < 16; ++r) {
                const int o = nb * 128 + nc * 64 + ni * 32 +
                              (r & 3) + 8 * (r >> 2) + 4 * kh;
                ob[(size_t)o * 4096 + px] = acc[mi][ni][r];
            }
        }
    }
}

extern "C" void kernel_launch(void* const* d_in, const int* in_sizes, int n_in,
                              void* d_out, int out_size, void* d_ws, size_t ws_size,
                              hipStream_t stream) {
    const float* x   = (const float*)d_in[0];
    const float* fcw = (const float*)d_in[1];
    float* out = (float*)d_out;
    u16* wg    = (u16*)d_ws;                              // 1.21 MB
    u32* runpk = (u32*)((char*)d_ws + RUNPK_OFF);         // 288 B

    hipLaunchKernelGGL(pack_w, dim3(WG_U16 / 1024), dim3(1024), 0, stream,
                       fcw, wg, runpk);
    hipLaunchKernelGGL(quad_gemm, dim3(512), dim3(256), 0, stream,
                       x, wg, runpk, out);
}

// Round 8
// 113.330 us; speedup vs baseline: 1.1670x; 1.0118x over previous
//
#include <hip/hip_runtime.h>

using u16 = unsigned short;
using u32 = unsigned int;

typedef __attribute__((ext_vector_type(8)))  short s16x8;
typedef __attribute__((ext_vector_type(4)))  float f32x4;
typedef __attribute__((ext_vector_type(16))) float f32x16;
typedef __attribute__((ext_vector_type(4)))  u32   u32x4;
typedef __attribute__((ext_vector_type(4)))  short s16x4;

#define NQ  74       // K chunks of 32 (2368 padded features)
#define NQQ 72       // quad chunks (column-major jr blocks); 72,73 = linear
#define WG_U16   (NQ * 8192)         // 606208 bf16 weights
#define RUNPK_OFF (WG_U16 * 2)       // byte offset of runpk[] in d_ws

__device__ __forceinline__ u16 f2bf_rne(float f) {
    u32 u = __builtin_bit_cast(u32, f);
    u32 r = u + 0x7fffu + ((u >> 16) & 1u);
    return (u16)(r >> 16);
}
__device__ __forceinline__ float bf2f(u16 u) {
    u32 v = ((u32)u) << 16;
    return __builtin_bit_cast(float, v);
}

// Column-major run schedule. Global run r (0..295):
//  r < 288: quad. chunk c=r>>2 lies in jr-block [jr(jr+1), (jr+1)(jr+2));
//           i = 4*(c - jr(jr+1)) + (r&3), j0 = 8*jr.  (j<i elems zero-padded)
//  r >= 288: linear (i = "ones"), j0 = 8*(r-288).
__device__ __forceinline__ void cm_decode(int r, int& i, int& j0) {
    if (r >= 288) { i = 64; j0 = (r - 288) * 8; return; }
    int c = r >> 2;
    int jr = 0;
    while (jr < 7 && (jr + 1) * (jr + 2) <= c) ++jr;
    i  = 4 * (c - jr * (jr + 1)) + (r & 3);
    j0 = 8 * jr;
}

// fc_w [256][2144] f32 -> wg bf16, flat idx
//   g = q*8192 + nb*4096 + nc*2048 + s*1024 + ni*512 + l*8 + e
// out-row n = nb*128 + nc*64 + ni*32 + (l&31); run = q*4 + 2s + (l>>5); elem e.
__global__ __launch_bounds__(1024)
void pack_w(const float* __restrict__ fcw, u16* __restrict__ wg,
            u32* __restrict__ runpk) {
    const u32 g = blockIdx.x * 1024 + threadIdx.x;
    if (blockIdx.x == 0 && threadIdx.x < NQQ) {
        int q = threadIdx.x, jr = 0;
        while (jr < 7 && (jr + 1) * (jr + 2) <= q) ++jr;
        runpk[q] = ((u32)(8 * jr) << 8) | (u32)(4 * (q - jr * (jr + 1)));
    }
    const int e  = g & 7;
    const int l  = (g >> 3) & 63;
    const int kh = l >> 5;
    const int ni = (g >> 9) & 1, s = (g >> 10) & 1;
    const int nc = (g >> 11) & 1, nb = (g >> 12) & 1;
    const int q  = g >> 13;
    int i, j0; cm_decode(q * 4 + 2 * s + kh, i, j0);
    const int n = nb * 128 + nc * 64 + ni * 32 + (l & 31);
    const int j = j0 + e;
    float w;
    if (i == 64)    w = fcw[n * 2144 + j];                                     // linear
    else if (j < i) w = 0.f;                                                   // pad
    else            w = fcw[n * 2144 + 64 + i * 64 - ((i * (i - 1)) >> 1) + (j - i)];
    wg[g] = f2bf_rne(w);
}

// y[e] = fi * x[j0+e], f32 mul + truncating bf16 pack (R1-R4/R7 proven)
__device__ __forceinline__ s16x8 packmul(float fi, s16x8 vj) {
    u32 pk[4];
    #pragma unroll
    for (int d = 0; d < 4; ++d) {
        float p0 = fi * bf2f((u16)vj[2 * d]);
        float p1 = fi * bf2f((u16)vj[2 * d + 1]);
        pk[d] = __builtin_amdgcn_perm(__builtin_bit_cast(u32, p1),
                                      __builtin_bit_cast(u32, p0), 0x07060302u);
    }
    u32x4 pv = { pk[0], pk[1], pk[2], pk[3] };
    return __builtin_bit_cast(s16x8, pv);
}

__global__ __launch_bounds__(256, 2)
void quad_gemm(const float* __restrict__ x, const u16* __restrict__ wg,
               const u32* __restrict__ runpk, float* __restrict__ out) {
    __shared__ __align__(16) u16 xl[128 * 64];   // bf16 [px][c ^ ((px&7)<<3)]
    __shared__ __align__(16) u16 x_t[64 * 128];  // bf16 [c][px] (fi reads)
    __shared__ u32 runl[NQQ];

    const int t  = threadIdx.x;
    const int l  = t & 63;
    const int wv = t >> 6;            // 4 waves: 2 mrow x 2 nc
    const int mrow = wv >> 1, nc = wv & 1;
    const int lm = l & 31, kh = l >> 5;
    const int sw = (lm & 7) << 3;

    const int mtile = (int)blockIdx.x >> 1;
    const int nb    = blockIdx.x & 1;         // N half (128 outputs)
    const int pix0  = mtile * 128;
    const int b     = pix0 >> 12;
    const int hw0   = pix0 & 4095;

    if (t < NQQ) runl[t] = runpk[t];

    // ---- stage x tile (128 px x 64 ch), f32 -> bf16, both layouts
    {
        const int mg = (t & 31) * 4;          // 4 consecutive pixels
        const int cg = (t >> 5) * 8;          // 8 consecutive channels
        const float* xp = x + ((size_t)b << 18) + (size_t)cg * 4096 + hw0 + mg;
        f32x4 vv[8];
        #pragma unroll
        for (int e = 0; e < 8; ++e)
            vv[e] = *(const f32x4*)(xp + (size_t)e * 4096);
        u16 tb[8][4];
        #pragma unroll
        for (int e = 0; e < 8; ++e)
            #pragma unroll
            for (int r = 0; r < 4; ++r) tb[e][r] = f2bf_rne(vv[e][r]);
        #pragma unroll
        for (int r = 0; r < 4; ++r) {
            int m = mg + r;
            u32x4 pv = { (u32)tb[0][r] | ((u32)tb[1][r] << 16),
                         (u32)tb[2][r] | ((u32)tb[3][r] << 16),
                         (u32)tb[4][r] | ((u32)tb[5][r] << 16),
                         (u32)tb[6][r] | ((u32)tb[7][r] << 16) };
            *(u32x4*)(xl + m * 64 + (cg ^ ((m & 7) << 3))) = pv;
        }
        #pragma unroll
        for (int e = 0; e < 8; ++e) {
            s16x4 pv = { (short)tb[e][0], (short)tb[e][1],
                         (short)tb[e][2], (short)tb[e][3] };
            *(s16x4*)(x_t + ((cg + e) << 7) + mg) = pv;
        }
    }

    const int pxb = mrow * 64 + lm;
    const u16* wp = wg + (size_t)(nb * 2 + nc) * 2048 + (size_t)l * 8;

    f32x16 acc[2][2];
    #pragma unroll
    for (int mi = 0; mi < 2; ++mi)
        #pragma unroll
        for (int ni = 0; ni < 2; ++ni)
            #pragma unroll
            for (int r = 0; r < 16; ++r) acc[mi][ni][r] = 0.f;

    // W chunk -> 4 frags in regs (W[s*2+ni]), coalesced dwordx4 from L2
    #define LOADW(Q, W) do {                                                 \
        int qc_ = (Q) < NQ ? (Q) : (NQ - 1);                                 \
        const u32x4* p_ = (const u32x4*)(wp + (size_t)qc_ * 8192);           \
        W[0] = p_[0]; W[1] = p_[64]; W[2] = p_[128]; W[3] = p_[192];         \
    } while (0)

    // Y frags for chunk Q (Y[mi*2+s]): per-lane from resident xl/x_t
    #define GENQ(Q, Y) do {                                                  \
        if ((Q) < NQQ) {                                                     \
            u32 meta_ = runl[(Q)];                                           \
            int j0_ = (int)((meta_ >> 8) & 255u), ib_ = (int)(meta_ & 255u); \
            _Pragma("unroll")                                                \
            for (int mi_ = 0; mi_ < 2; ++mi_) {                              \
                int px_ = pxb + mi_ * 32;                                    \
                s16x8 vj_ = *(const s16x8*)(xl + (px_ << 6) + (j0_ ^ sw));   \
                float f0_ = bf2f(x_t[((ib_ + kh) << 7) + px_]);              \
                float f1_ = bf2f(x_t[((ib_ + 2 + kh) << 7) + px_]);          \
                Y[mi_ * 2 + 0] = packmul(f0_, vj_);                          \
                Y[mi_ * 2 + 1] = packmul(f1_, vj_);                          \
            }                                                                \
        } else {                                                             \
            int cb_ = ((Q) - NQQ) * 32;                                      \
            _Pragma("unroll")                                                \
            for (int mi_ = 0; mi_ < 2; ++mi_) {                              \
                int base_ = (pxb + mi_ * 32) << 6;                           \
                _Pragma("unroll")                                            \
                for (int s_ = 0; s_ < 2; ++s_) {                             \
                    int j0_ = cb_ + 8 * (2 * s_ + kh);                       \
                    Y[mi_ * 2 + s_] =                                        \
                        *(const s16x8*)(xl + base_ + (j0_ ^ sw));            \
                }                                                            \
            }                                                                \
        }                                                                    \
    } while (0)

    #define MFMAQ(W, Y) do {                                                 \
        _Pragma("unroll")                                                    \
        for (int s_ = 0; s_ < 2; ++s_)                                       \
            _Pragma("unroll")                                                \
            for (int mi_ = 0; mi_ < 2; ++mi_)                                \
                _Pragma("unroll")                                            \
                for (int ni_ = 0; ni_ < 2; ++ni_)                            \
                    acc[mi_][ni_] = __builtin_amdgcn_mfma_f32_32x32x16_bf16( \
                        __builtin_bit_cast(s16x8, W[s_ * 2 + ni_]),          \
                        Y[mi_ * 2 + s_],                                     \
                        acc[mi_][ni_], 0, 0, 0);                             \
    } while (0)

    u32x4 W0[4], W1[4], W2[4], W3[4];
    s16x8 Ya[4], Yb[4];

    LOADW(0, W0); LOADW(1, W1); LOADW(2, W2); LOADW(3, W3);
    __syncthreads();          // xl/x_t/runl ready; the ONLY barrier
    GENQ(0, Ya);

    // 4-deep W pipeline: buffer reloaded right after its last use,
    // prefetch distance ~4 chunk-phases. 72 = 4*18 main-loop chunks.
    #pragma unroll 1
    for (int q = 0; q < 72; q += 4) {
        GENQ(q + 1, Yb); MFMAQ(W0, Ya); LOADW(q + 4, W0);
        GENQ(q + 2, Ya); MFMAQ(W1, Yb); LOADW(q + 5, W1);
        GENQ(q + 3, Yb); MFMAQ(W2, Ya); LOADW(q + 6, W2);
        GENQ(q + 4, Ya); MFMAQ(W3, Yb); LOADW(q + 7, W3);
    }
    // after loop: Ya holds chunk 72; W0 holds 72, W1 holds 73
    GENQ(73, Yb);
    MFMAQ(W0, Ya);
    MFMAQ(W1, Yb);

    // D: col = lane&31 -> pixel; row = (r&3) + 8*(r>>2) + 4*kh -> out channel
    float* ob = out + ((size_t)b << 20) + (size_t)hw0;
    #pragma unroll
    for (int mi = 0; mi < 2; ++mi) {
        const int px = pxb + mi * 32;
        #pragma unroll
        for (int ni = 0; ni < 2; ++ni) {
            #pragma unroll
            for (int r = 0; r < 16; ++r) {
                const int o = nb * 128 + nc * 64 + ni * 32 +
                              (r & 3) + 8 * (r >> 2) + 4 * kh;
                ob[(size_t)o * 4096 + px] = acc[mi][ni][r];
            }
        }
    }
}

extern "C" void kernel_launch(void* const* d_in, const int* in_sizes, int n_in,
                              void* d_out, int out_size, void* d_ws, size_t ws_size,
                              hipStream_t stream) {
    const float* x   = (const float*)d_in[0];
    const float* fcw = (const float*)d_in[1];
    float* out = (float*)d_out;
    u16* wg    = (u16*)d_ws;                              // 1.21 MB
    u32* runpk = (u32*)((char*)d_ws + RUNPK_OFF);         // 288 B

    hipLaunchKernelGGL(pack_w, dim3(WG_U16 / 1024), dim3(1024), 0, stream,
                       fcw, wg, runpk);
    hipLaunchKernelGGL(quad_gemm, dim3(512), dim3(256), 0, stream,
                       x, wg, runpk, out);
}